// Round 4
// baseline (236.088 us; speedup 1.0000x reference)
//
#include <hip/hip_runtime.h>
#include <hip/hip_bf16.h>
#include <math.h>

constexpr int Bb = 2, Hh = 16, Tt = 2048;

typedef __attribute__((ext_vector_type(8))) _Float16 f16x8;
typedef __attribute__((ext_vector_type(8))) short bf16x8;
typedef __attribute__((ext_vector_type(4))) float f32x4;
typedef __attribute__((ext_vector_type(4))) short short4v;

__device__ __forceinline__ short f2bf(float x){ __hip_bfloat16 h = __float2bfloat16(x); return *(short*)&h; }
__device__ __forceinline__ float bf2f(short s){ __hip_bfloat16 h; *(short*)&h = s; return __bfloat162float(h); }

// LDS swizzle helpers (row-major 64-elem rows, 8-elem granules XORed by row&7)
__device__ __forceinline__ int swze(int row, int e){ return row*64 + ((((e>>3) ^ (row&7))<<3) | (e&7)); }
__device__ __forceinline__ int swzg(int row, int e0){ return row*64 + ((((e0>>3) ^ (row&7))<<3)); }

// ---------- pre-pass 1: E fp32 -> f16 hi/lo planes (natural [h][s][d] layout) ----------
__global__ __launch_bounds__(256) void prep_e(const float* __restrict__ E,
                                              _Float16* __restrict__ Ehg, _Float16* __restrict__ Elg){
  const size_t base = ((size_t)blockIdx.x * 256 + threadIdx.x) * 8;
  float4 a = *(const float4*)(E + base);
  float4 c = *(const float4*)(E + base + 4);
  float v[8] = {a.x, a.y, a.z, a.w, c.x, c.y, c.z, c.w};
  f16x8 hv, lv;
#pragma unroll
  for (int j = 0; j < 8; ++j) {
    _Float16 hi = (_Float16)v[j];
    hv[j] = hi;
    lv[j] = (_Float16)(v[j] - (float)hi);
  }
  *(f16x8*)(Ehg + base) = hv;
  *(f16x8*)(Elg + base) = lv;
}

// ---------- pre-pass 2: V fp32 [bh][s][d] -> bf16 transposed [bh][d][s] ----------
__global__ __launch_bounds__(256) void prep_v(const float* __restrict__ V, short* __restrict__ Vt){
  __shared__ __align__(16) short Tl[64 * 64];
  const int tid = threadIdx.x;
  const int tile = blockIdx.x & 31, bh = blockIdx.x >> 5;
  const int s0 = tile * 64;
  {
    const int r = tid >> 2, c0 = (tid & 3) * 16;
    const float* src = V + ((size_t)bh * Tt + s0 + r) * 64 + c0;
#pragma unroll
    for (int i = 0; i < 4; ++i) {
      float4 t4 = ((const float4*)src)[i];
      float vv[4] = {t4.x, t4.y, t4.z, t4.w};
#pragma unroll
      for (int j = 0; j < 4; ++j) Tl[swze(c0 + 4 * i + j, r)] = f2bf(vv[j]);
    }
  }
  __syncthreads();
  {
    const int d = tid >> 2, sg = (tid & 3) * 16;
    bf16x8 a = *(const bf16x8*)&Tl[swzg(d, sg)];
    bf16x8 b = *(const bf16x8*)&Tl[swzg(d, sg + 8)];
    short* dst = Vt + ((size_t)bh * 64 + d) * Tt + s0 + sg;
    *(bf16x8*)dst = a;
    *(bf16x8*)(dst + 8) = b;
  }
}

// ---------- main kernel: barrier-free flash LIF-attention ----------
__global__ __launch_bounds__(256) void lif_attn3(
    const float* __restrict__ Q, const float* __restrict__ gain, const float* __restrict__ bias,
    const _Float16* __restrict__ Ehg, const _Float16* __restrict__ Elg,
    const short* __restrict__ Vtg, float* __restrict__ out)
{
  __shared__ __align__(16) short Pl[64 * 64];   // P rows, wave-private 16-row strips
  __shared__ __align__(16) float Ls[64];

  const int tid = threadIdx.x, lane = tid & 63, w = tid >> 6;
  const int lrow = lane & 15, g = lane >> 4;
  const int bh = blockIdx.x & 31, tb = 31 - (blockIdx.x >> 5);  // big tiles first
  const int b = bh >> 4, h = bh & 15, t0 = tb * 64;
  const int t = t0 + 16 * w + lrow;   // this lane's query row (S^T column)

  // Q fragments (f16 hi/lo) straight from global, loop-invariant
  const float* qp = Q + ((size_t)(b * Hh + h) * Tt + t) * 64;
  f16x8 qh[2], ql[2];
#pragma unroll
  for (int kk = 0; kk < 2; ++kk) {
    const float* p0 = qp + 32 * kk + 8 * g;
    float4 a = *(const float4*)p0;
    float4 c = *(const float4*)(p0 + 4);
    float v[8] = {a.x, a.y, a.z, a.w, c.x, c.y, c.z, c.w};
#pragma unroll
    for (int j = 0; j < 8; ++j) {
      _Float16 hi = (_Float16)v[j];
      qh[kk][j] = hi;
      ql[kk][j] = (_Float16)(v[j] - (float)hi);
    }
  }

  const float gt = gain[h * Tt + t];
  const float bt = bias[h * Tt + t];

  const _Float16* ehb = Ehg + (size_t)h * Tt * 64;
  const _Float16* elb = Elg + (size_t)h * Tt * 64;
  const short* vtb = Vtg + (size_t)(b * Hh + h) * 64 * Tt;

  const int prow = 16 * w + lrow;
  const int pswz = (lrow & 7) << 4;
  char* plb = (char*)Pl + prow * 128;

  const f32x4 fzero = {0.f, 0.f, 0.f, 0.f};
  f32x4 oacc[4];
#pragma unroll
  for (int c = 0; c < 4; ++c) oacc[c] = fzero;
  float lsum = 0.f;

  for (int s0 = 0; s0 <= t0; s0 += 64) {
    // ---- S^T = E · Q^T  (split f16: hh + hl + lh), rows = s, cols = t ----
    f32x4 sacc[4];
#pragma unroll
    for (int c = 0; c < 4; ++c) sacc[c] = fzero;
#pragma unroll
    for (int c = 0; c < 4; ++c) {
      const size_t ro = (size_t)(s0 + 16 * c + lrow) * 64 + 8 * g;
#pragma unroll
      for (int kk = 0; kk < 2; ++kk) {
        f16x8 eh = *(const f16x8*)(ehb + ro + 32 * kk);
        f16x8 el = *(const f16x8*)(elb + ro + 32 * kk);
        sacc[c] = __builtin_amdgcn_mfma_f32_16x16x32_f16(eh, qh[kk], sacc[c], 0, 0, 0);
        sacc[c] = __builtin_amdgcn_mfma_f32_16x16x32_f16(eh, ql[kk], sacc[c], 0, 0, 0);
        sacc[c] = __builtin_amdgcn_mfma_f32_16x16x32_f16(el, qh[kk], sacc[c], 0, 0, 0);
      }
    }

    // ---- LIF + fixed-shift exp; pack 4 consecutive s per b64 LDS write ----
    // score = 0.125 / (tau_ref - tau_rc*ln((I-1)/I)), bounded (0, 62.5];
    // non-firing entries keep score 0 -> weight exp(0-62.5), NOT zero.
#pragma unroll
    for (int c = 0; c < 4; ++c) {
      short4v pb;
#pragma unroll
      for (int reg = 0; reg < 4; ++reg) {
        const int s = s0 + 16 * c + 4 * g + reg;
        const float I = fmaf(gt, sacc[c][reg], bt);
        const float num = I - 1.0f;                        // exact for I in (1,2); >0 iff firing
        const float L = __logf(num * __builtin_amdgcn_rcpf(I));  // ln((I-1)/I) < 0, NaN-safe for firing I
        const float den = fmaf(-0.02f, L, 0.002f);         // tau_ref - tau_rc*ln(...)  > 0.002
        const float score = 0.125f * __builtin_amdgcn_rcpf(den);
        float p = __expf(score - 62.5f);
        p = (I > 1.0f + 1e-7f) ? p : 7.1892e-28f;          // non-firing: exp(0 - 62.5)
        p = (s <= t) ? p : 0.f;                            // causal mask
        const short pbv = f2bf(p);
        lsum += bf2f(pbv);          // denominator sums exactly what PV consumes
        pb[reg] = pbv;
      }
      *(short4v*)(plb + ((32 * c + 8 * g) ^ pswz)) = pb;
    }
    // order the wave-internal P write -> read (cross-lane through LDS)
    asm volatile("s_waitcnt lgkmcnt(0)" ::: "memory");
    __builtin_amdgcn_sched_barrier(0);

    // ---- PV: oacc += P · V ----
    bf16x8 pa[2];
#pragma unroll
    for (int kk = 0; kk < 2; ++kk)
      pa[kk] = *(bf16x8*)(plb + ((64 * kk + 16 * g) ^ pswz));
#pragma unroll
    for (int c = 0; c < 4; ++c) {
      const short* vp = vtb + (size_t)(16 * c + lrow) * Tt + s0 + 8 * g;
#pragma unroll
      for (int kk = 0; kk < 2; ++kk) {
        bf16x8 vb = *(const bf16x8*)(vp + 32 * kk);
        oacc[c] = __builtin_amdgcn_mfma_f32_16x16x32_bf16(pa[kk], vb, oacc[c], 0, 0, 0);
      }
    }
  }

  // ---- epilogue: row sums, normalize, store ----
  lsum += __shfl_xor(lsum, 16);
  lsum += __shfl_xor(lsum, 32);
  if (lane < 16) Ls[16 * w + lane] = lsum;
  __syncthreads();
  f32x4 lv = *(f32x4*)&Ls[16 * w + 4 * g];
  float linv[4];
#pragma unroll
  for (int r = 0; r < 4; ++r) linv[r] = 1.f / lv[r];

  float* ob = out + ((size_t)(b * Hh + h) * Tt + t0 + 16 * w) * 64 + lrow;
#pragma unroll
  for (int c = 0; c < 4; ++c)
#pragma unroll
    for (int r = 0; r < 4; ++r)
      ob[(size_t)(4 * g + r) * 64 + 16 * c] = oacc[c][r] * linv[r];
}

extern "C" void kernel_launch(void* const* d_in, const int* in_sizes, int n_in,
                              void* d_out, int out_size, void* d_ws, size_t ws_size,
                              hipStream_t stream) {
  const float* Q    = (const float*)d_in[0];
  // d_in[1] = K is UNUSED by the reference (scores use enc_hat)
  const float* V    = (const float*)d_in[2];
  const float* E    = (const float*)d_in[3];
  const float* gain = (const float*)d_in[4];
  const float* bias = (const float*)d_in[5];
  float* out = (float*)d_out;

  constexpr size_t EH_BYTES = (size_t)Hh * Tt * 64 * 2;        // 4 MiB
  constexpr size_t VT_BYTES = (size_t)Bb * Hh * 64 * Tt * 2;   // 8 MiB

  _Float16* Ehg = (_Float16*)d_ws;
  _Float16* Elg = (_Float16*)((char*)d_ws + EH_BYTES);
  short*    Vtg = (short*)((char*)d_ws + 2 * EH_BYTES);
  prep_e<<<1024, 256, 0, stream>>>(E, Ehg, Elg);
  prep_v<<<1024, 256, 0, stream>>>(V, Vtg);
  lif_attn3<<<1024, 256, 0, stream>>>(Q, gain, bias, Ehg, Elg, Vtg, out);
}

// Round 5
// 85.953 us; speedup vs baseline: 2.7467x; 2.7467x over previous
//
#include <hip/hip_runtime.h>
#include <hip/hip_bf16.h>
#include <math.h>

constexpr int Bb = 2, Hh = 16, Tt = 2048;

typedef __attribute__((ext_vector_type(8))) _Float16 f16x8;
typedef __attribute__((ext_vector_type(8))) short bf16x8;
typedef __attribute__((ext_vector_type(4))) float f32x4;
typedef __attribute__((ext_vector_type(16))) float f32x16;
typedef __attribute__((ext_vector_type(4))) short short4v;
typedef unsigned int u32;

__device__ __forceinline__ short f2bf(float x){ __hip_bfloat16 h = __float2bfloat16(x); return *(short*)&h; }
__device__ __forceinline__ float bf2f(short s){
  u32 u = ((u32)(unsigned short)s) << 16; float f; __builtin_memcpy(&f, &u, 4); return f;
}
// generic 64-elem-row swizzle helpers (used by prep_v's internal transpose)
__device__ __forceinline__ int swze(int row, int e){ return row*64 + ((((e>>3) ^ (row&7))<<3) | (e&7)); }
__device__ __forceinline__ int swzg(int row, int e0){ return row*64 + ((((e0>>3) ^ (row&7))<<3)); }

__device__ __forceinline__ void gll16(const void* g, void* l){
  __builtin_amdgcn_global_load_lds((const __attribute__((address_space(1))) u32*)g,
                                   (__attribute__((address_space(3))) u32*)l, 16, 0, 0);
}

// ---------- prep 1: E fp32 -> f16 hi/lo 64x64 tile images, XOR-swizzled (LDS byte-exact) ----------
// image tile (h,j): 16384 B = [hi 8192][lo 8192]; granule(row r, content-granule gc 0..7)
// at plane + r*128 + ((gc ^ (r&7))<<4), holding E[r][8*gc .. 8*gc+7]
__global__ __launch_bounds__(256) void prep_e(const float* __restrict__ E, char* __restrict__ Eimg){
  const int hh = blockIdx.x >> 5, j = blockIdx.x & 31;
  const float* src = E + ((size_t)hh * Tt + j * 64) * 64;
  char* dst = Eimg + (size_t)blockIdx.x * 16384;
#pragma unroll
  for (int i = 0; i < 2; ++i) {
    const int gid = threadIdx.x + 256 * i;
    const int row = gid >> 3, gc = gid & 7;
    const float* s8 = src + row * 64 + gc * 8;
    float4 a = *(const float4*)s8;
    float4 c = *(const float4*)(s8 + 4);
    float v[8] = {a.x, a.y, a.z, a.w, c.x, c.y, c.z, c.w};
    f16x8 hv, lv;
#pragma unroll
    for (int k = 0; k < 8; ++k) {
      _Float16 hi = (_Float16)v[k];
      hv[k] = hi; lv[k] = (_Float16)(v[k] - (float)hi);
    }
    const int off = row * 128 + ((gc ^ (row & 7)) << 4);
    *(f16x8*)(dst + off) = hv;
    *(f16x8*)(dst + 8192 + off) = lv;
  }
}

// ---------- prep 2: V fp32 [bh][s][d] -> bf16 transposed 64x64 tile images Vt[d][s], swizzled ----------
__global__ __launch_bounds__(256) void prep_v(const float* __restrict__ V, char* __restrict__ Vimg){
  __shared__ __align__(16) short Tl[64 * 64];
  const int tid = threadIdx.x;
  const int j = blockIdx.x & 31, bh = blockIdx.x >> 5;
  const int s0 = j * 64;
  {
    const int r = tid >> 2, c0 = (tid & 3) * 16;
    const float* src = V + ((size_t)bh * Tt + s0 + r) * 64 + c0;
#pragma unroll
    for (int i = 0; i < 4; ++i) {
      float4 t4 = ((const float4*)src)[i];
      float vv[4] = {t4.x, t4.y, t4.z, t4.w};
#pragma unroll
      for (int k = 0; k < 4; ++k) Tl[swze(c0 + 4 * i + k, r)] = f2bf(vv[k]);
    }
  }
  __syncthreads();
  {
    const int d = tid >> 2, sg = (tid & 3) * 16;
    bf16x8 a = *(const bf16x8*)&Tl[swzg(d, sg)];
    bf16x8 b = *(const bf16x8*)&Tl[swzg(d, sg + 8)];
    char* dst = Vimg + (size_t)blockIdx.x * 8192 + d * 128;
    *(bf16x8*)(dst + ((((sg >> 3) + 0) ^ (d & 7)) << 4)) = a;
    *(bf16x8*)(dst + ((((sg >> 3) + 1) ^ (d & 7)) << 4)) = b;
  }
}

// ---------- main: 32x32-MFMA flash LIF-attention, async-staged, counted-vmcnt pipeline ----------
__global__ __launch_bounds__(256, 3) void lif_attn5(
    const float* __restrict__ Q, const float* __restrict__ gain, const float* __restrict__ bias,
    const char* __restrict__ Eimg, const char* __restrict__ Vimg, float* __restrict__ out)
{
  __shared__ __align__(16) char Eb[2][16384];   // E tile hi+lo, double-buffered
  __shared__ __align__(16) char Vb[8192];       // Vt tile (single buffer, counted-vmcnt)
  __shared__ __align__(16) char Pb[8192];       // P (bf16), cross-wave shared
  __shared__ __align__(16) float Ls[128];       // lsum partials [wr][t_local]

  const int tid = threadIdx.x, lane = tid & 63, w = tid >> 6;
  const int l31 = lane & 31, hi2 = lane >> 5;
  const int wr = w >> 1, wc = w & 1;            // s-half / t-half (S^T); d-half / t-half (PV)
  const int bh = blockIdx.x & 31, tb = 31 - (blockIdx.x >> 5);  // big tiles dispatched first
  const int b = bh >> 4, h = bh & 15, t0 = tb * 64;
  const int tg = t0 + 32 * wc + l31;            // this lane's query row

  const char* etile = Eimg + (size_t)(h * 32) * 16384;
  const char* vtile = Vimg + (size_t)(bh * 32) * 8192;

  // ---- Q fragments f16 hi/lo (loop-invariant, B-operand: mem[t][k]) ----
  f16x8 qh[4], ql[4];
  {
    const float* qp = Q + ((size_t)(b * Hh + h) * Tt + tg) * 64 + 8 * hi2;
#pragma unroll
    for (int kk = 0; kk < 4; ++kk) {
      const float* p0 = qp + 16 * kk;
      float4 a = *(const float4*)p0;
      float4 c = *(const float4*)(p0 + 4);
      float v[8] = {a.x, a.y, a.z, a.w, c.x, c.y, c.z, c.w};
#pragma unroll
      for (int k = 0; k < 8; ++k) {
        _Float16 hi = (_Float16)v[k];
        qh[kk][k] = hi; ql[kk][k] = (_Float16)(v[k] - (float)hi);
      }
    }
  }
  const float gt = gain[h * Tt + tg], bt = bias[h * Tt + tg];

  // per-lane LDS byte bases; fragment addr = base XOR (kk<<5) (swizzle algebra)
  const int rE = 32 * wr + l31;                               // E/Vt row this lane reads
  const int eB = rE * 128 + ((hi2 ^ (rE & 7)) << 4);
  const int vB = eB;                                          // same row pattern for Vt
  const int tl = 32 * wc + l31;                               // P row (t-local)
  const int pB = tl * 128 + ((hi2 ^ (tl & 7)) << 4);
  const int pwB = (tl * 128 + ((tl & 7) << 4) + 8 * hi2) ^ (wr << 6);  // P write: ^ (rq<<4)

  f32x16 oacc = 0.f;
  float lsum = 0.f;

  // prologue: stage tile 0 (E then V), wait own E, barrier
  {
    const char* g = etile + tid * 16; char* l = &Eb[0][0] + tid * 16;
#pragma unroll
    for (int c = 0; c < 4; ++c) gll16(g + c * 4096, l + c * 4096);
    const char* gv = vtile + tid * 16; char* lv2 = &Vb[0] + tid * 16;
#pragma unroll
    for (int c = 0; c < 2; ++c) gll16(gv + c * 4096, lv2 + c * 4096);
  }
  asm volatile("s_waitcnt vmcnt(2)" ::: "memory");
  __builtin_amdgcn_s_barrier();
  asm volatile("" ::: "memory");
  __builtin_amdgcn_sched_barrier(0);

  int cur = 0;
  for (int j = 0;;) {
    const int jn = (j < tb) ? j + 1 : tb;
    // 1) issue E(j+1) prefetch into the other buffer (4 x global_load_lds)
    {
      const char* g = etile + (size_t)jn * 16384 + tid * 16;
      char* l = &Eb[cur ^ 1][0] + tid * 16;
#pragma unroll
      for (int c = 0; c < 4; ++c) gll16(g + c * 4096, l + c * 4096);
    }
    // 2) S^T = E·Q^T (split f16: hh + lh + hl), wave quadrant (32 s) x (32 t)
    const char* ec = &Eb[cur][0];
    f32x16 sacc = 0.f;
#pragma unroll
    for (int kk = 0; kk < 4; ++kk) {
      f16x8 eh = *(const f16x8*)(ec + (eB ^ (kk << 5)));
      f16x8 el = *(const f16x8*)(ec + 8192 + (eB ^ (kk << 5)));
      sacc = __builtin_amdgcn_mfma_f32_32x32x16_f16(eh, qh[kk], sacc, 0, 0, 0);
      sacc = __builtin_amdgcn_mfma_f32_32x32x16_f16(el, qh[kk], sacc, 0, 0, 0);
      sacc = __builtin_amdgcn_mfma_f32_32x32x16_f16(eh, ql[kk], sacc, 0, 0, 0);
    }
    // 3) LIF + fixed-shift exp -> P (bf16, b64 writes); row-sum accumulates
    const int s0 = j * 64;
#pragma unroll
    for (int rq = 0; rq < 4; ++rq) {
      short4v pb;
#pragma unroll
      for (int rr = 0; rr < 4; ++rr) {
        const int sg = s0 + 32 * wr + 8 * rq + 4 * hi2 + rr;
        const float I = fmaf(gt, sacc[4 * rq + rr], bt);
        const float rcpI = __builtin_amdgcn_rcpf(I);
        const float L2 = __log2f((I - 1.0f) * rcpI);           // log2((I-1)/I), NaN-safe for firing I
        const float den = fmaf(-0.013862944f, L2, 0.002f);     // tau_ref - tau_rc*ln((I-1)/I)
        const float rd = __builtin_amdgcn_rcpf(den);
        float p = __expf(fmaf(0.125f, rd, -62.5f));            // exp(score - SHIFT)
        p = (I > 1.0f + 1e-7f) ? p : 7.1892351e-28f;           // non-firing: exp(0 - 62.5)
        p = (sg <= tg) ? p : 0.0f;                             // causal
        const short pv = f2bf(p);
        lsum += bf2f(pv);                                      // sum exactly what PV consumes
        pb[rr] = pv;
      }
      *(short4v*)(&Pb[0] + (pwB ^ (rq << 4))) = pb;
    }
    // 4) P visible to sibling waves + Vt(j) staged by all waves (counted vmcnt: E(j+1) stays in flight)
    asm volatile("s_waitcnt vmcnt(4) lgkmcnt(0)" ::: "memory");
    __builtin_amdgcn_s_barrier();
    asm volatile("" ::: "memory");
    __builtin_amdgcn_sched_barrier(0);
    // 5) PV: oacc += P·V, wave quadrant (32 t) x (32 d)
#pragma unroll
    for (int kk = 0; kk < 4; ++kk) {
      bf16x8 pa = *(const bf16x8*)(&Pb[0] + (pB ^ (kk << 5)));
      bf16x8 vb = *(const bf16x8*)(&Vb[0] + (vB ^ (kk << 5)));
      oacc = __builtin_amdgcn_mfma_f32_32x32x16_bf16(pa, vb, oacc, 0, 0, 0);
    }
    // 6) E(j+1) complete (full tile of cover) + WAR fence, then issue Vt(j+1)
    asm volatile("s_waitcnt vmcnt(0)" ::: "memory");
    __builtin_amdgcn_s_barrier();
    asm volatile("" ::: "memory");
    __builtin_amdgcn_sched_barrier(0);
    if (j == tb) break;
    {
      const char* g = vtile + (size_t)jn * 8192 + tid * 16;
      char* l = &Vb[0] + tid * 16;
#pragma unroll
      for (int c = 0; c < 2; ++c) gll16(g + c * 4096, l + c * 4096);
    }
    cur ^= 1; ++j;
  }

  // ---- epilogue: combine lsum partials (hi2 halves via shfl, wr halves via LDS), normalize, store ----
  lsum += __shfl_xor(lsum, 32);
  __syncthreads();
  Ls[wr * 64 + tl] = lsum;
  __syncthreads();
  float* ob = out + ((size_t)(b * Hh + h) * Tt + t0) * 64 + 32 * wr + l31;  // d-offset = 32*wr
#pragma unroll
  for (int rq = 0; rq < 4; ++rq) {
    const int tr = 32 * wc + 8 * rq + 4 * hi2;
    f32x4 la = *(const f32x4*)&Ls[tr];
    f32x4 lb = *(const f32x4*)&Ls[64 + tr];
#pragma unroll
    for (int rr = 0; rr < 4; ++rr) {
      const float linv = __builtin_amdgcn_rcpf(la[rr] + lb[rr]);
      ob[(size_t)(tr + rr) * 64] = oacc[4 * rq + rr] * linv;
    }
  }
}

extern "C" void kernel_launch(void* const* d_in, const int* in_sizes, int n_in,
                              void* d_out, int out_size, void* d_ws, size_t ws_size,
                              hipStream_t stream) {
  const float* Q    = (const float*)d_in[0];
  // d_in[1] = K is UNUSED by the reference (scores use enc_hat)
  const float* V    = (const float*)d_in[2];
  const float* E    = (const float*)d_in[3];
  const float* gain = (const float*)d_in[4];
  const float* bias = (const float*)d_in[5];
  float* out = (float*)d_out;

  constexpr size_t EIMG_BYTES = (size_t)Hh * 32 * 16384;        // 8 MiB
  char* Eimg = (char*)d_ws;
  char* Vimg = (char*)d_ws + EIMG_BYTES;                        // 8 MiB

  prep_e<<<Hh * 32, 256, 0, stream>>>(E, Eimg);
  prep_v<<<Bb * Hh * 32, 256, 0, stream>>>(V, Vimg);
  lif_attn5<<<1024, 256, 0, stream>>>(Q, gain, bias, Eimg, Vimg, out);
}

// Round 7
// 79.357 us; speedup vs baseline: 2.9750x; 1.0831x over previous
//
#include <hip/hip_runtime.h>
#include <hip/hip_bf16.h>
#include <math.h>

constexpr int Bb = 2, Hh = 16, Tt = 2048;

typedef __attribute__((ext_vector_type(8))) _Float16 f16x8;
typedef __attribute__((ext_vector_type(8))) short bf16x8;
typedef __attribute__((ext_vector_type(4))) float f32x4;
typedef __attribute__((ext_vector_type(16))) float f32x16;
typedef __attribute__((ext_vector_type(4))) unsigned int u32x4;
typedef unsigned int u32;

__device__ __forceinline__ short f2bf(float x){ __hip_bfloat16 h = __float2bfloat16(x); return *(short*)&h; }
// 64-elem-row swizzle helpers (prep_v's internal transpose)
__device__ __forceinline__ int swze(int row, int e){ return row*64 + ((((e>>3) ^ (row&7))<<3) | (e&7)); }
__device__ __forceinline__ int swzg(int row, int e0){ return row*64 + ((((e0>>3) ^ (row&7))<<3)); }

__device__ __forceinline__ void gll16(const void* g, void* l){
  __builtin_amdgcn_global_load_lds((const __attribute__((address_space(1))) u32*)g,
                                   (__attribute__((address_space(3))) u32*)l, 16, 0, 0);
}
__device__ __forceinline__ u32 cvtpk(float lo, float hi){
  u32 d; asm("v_cvt_pk_bf16_f32 %0, %1, %2" : "=v"(d) : "v"(lo), "v"(hi)); return d;
}

// ---------- prep 1: E fp32 -> f16 hi/lo 64x64 tile images, XOR-swizzled (LDS byte-exact) ----------
__global__ __launch_bounds__(256) void prep_e(const float* __restrict__ E, char* __restrict__ Eimg){
  const float* src = E + (size_t)blockIdx.x * 4096;
  char* dst = Eimg + (size_t)blockIdx.x * 16384;
#pragma unroll
  for (int i = 0; i < 2; ++i) {
    const int gid = threadIdx.x + 256 * i;
    const int row = gid >> 3, gc = gid & 7;
    const float* s8 = src + row * 64 + gc * 8;
    float4 a = *(const float4*)s8;
    float4 c = *(const float4*)(s8 + 4);
    float v[8] = {a.x, a.y, a.z, a.w, c.x, c.y, c.z, c.w};
    f16x8 hv, lv;
#pragma unroll
    for (int k = 0; k < 8; ++k) {
      _Float16 hi = (_Float16)v[k];
      hv[k] = hi; lv[k] = (_Float16)(v[k] - (float)hi);
    }
    const int off = row * 128 + ((gc ^ (row & 7)) << 4);
    *(f16x8*)(dst + off) = hv;
    *(f16x8*)(dst + 8192 + off) = lv;
  }
}

// ---------- prep 2: V fp32 [bh][s][d] -> bf16 transposed 64x64 tile images Vt[d][s], swizzled ----------
__global__ __launch_bounds__(256) void prep_v(const float* __restrict__ V, char* __restrict__ Vimg){
  __shared__ __align__(16) short Tl[64 * 64];
  const int tid = threadIdx.x;
  const int j = blockIdx.x & 31, bh = blockIdx.x >> 5;
  const int s0 = j * 64;
  {
    const int r = tid >> 2, c0 = (tid & 3) * 16;
    const float* src = V + ((size_t)bh * Tt + s0 + r) * 64 + c0;
#pragma unroll
    for (int i = 0; i < 4; ++i) {
      float4 t4 = ((const float4*)src)[i];
      float vv[4] = {t4.x, t4.y, t4.z, t4.w};
#pragma unroll
      for (int k = 0; k < 4; ++k) Tl[swze(c0 + 4 * i + k, r)] = f2bf(vv[k]);
    }
  }
  __syncthreads();
  {
    const int d = tid >> 2, sg = (tid & 3) * 16;
    bf16x8 a = *(const bf16x8*)&Tl[swzg(d, sg)];
    bf16x8 b = *(const bf16x8*)&Tl[swzg(d, sg + 8)];
    char* dst = Vimg + (size_t)blockIdx.x * 8192 + d * 128;
    *(bf16x8*)(dst + ((((sg >> 3) + 0) ^ (d & 7)) << 4)) = a;
    *(bf16x8*)(dst + ((((sg >> 3) + 1) ^ (d & 7)) << 4)) = b;
  }
}

// ---------- main: P-in-register flash LIF-attention (cvt_pk + permlane32_swap), 1 barrier/tile ----------
__global__ __launch_bounds__(256, 3) void lif_attn6(
    const float* __restrict__ Q, const float* __restrict__ gain, const float* __restrict__ bias,
    const char* __restrict__ Eimg, const char* __restrict__ Vimg, float* __restrict__ out)
{
  __shared__ __align__(16) char Eb[2][16384];   // E tile hi+lo, double-buffered (reused as f32 red[] in epilogue)
  __shared__ __align__(16) char Vb[2][8192];    // Vt tile, double-buffered
  __shared__ __align__(16) float LsS[128];      // lsum partials [wr][wc][t_in_half]

  const int tid = threadIdx.x, lane = tid & 63;
  const int l31 = lane & 31, hi2 = lane >> 5;
  const int w = tid >> 6, wc = w & 1, wr = w >> 1;  // wc = t-half; wr = s-half (S^T row AND PV k-range)
  const int bh = blockIdx.x & 31, tb = 31 - (blockIdx.x >> 5);  // big tiles dispatched first
  const int b = bh >> 4, h = bh & 15, t0 = tb * 64;
  const int tg = t0 + 32 * wc + l31;            // this lane's query row (S^T column / PV A-row)

  const char* etile = Eimg + (size_t)(h * 32) * 16384;
  const char* vtile = Vimg + (size_t)(bh * 32) * 8192;

  // ---- Q fragments f16 hi/lo (loop-invariant, B-operand: k = 16kk + 8hi2 + j) ----
  f16x8 qh[4], ql[4];
  {
    const float* qp = Q + ((size_t)(b * Hh + h) * Tt + tg) * 64 + 8 * hi2;
#pragma unroll
    for (int kk = 0; kk < 4; ++kk) {
      const float* p0 = qp + 16 * kk;
      float4 a = *(const float4*)p0;
      float4 c = *(const float4*)(p0 + 4);
      float v[8] = {a.x, a.y, a.z, a.w, c.x, c.y, c.z, c.w};
#pragma unroll
      for (int k = 0; k < 8; ++k) {
        _Float16 hi = (_Float16)v[k];
        qh[kk][k] = hi; ql[kk][k] = (_Float16)(v[k] - (float)hi);
      }
    }
  }
  const float gt = gain[h * Tt + tg], bt = bias[h * Tt + tg];

  // E read: row rS = 32wr + l31, granule 2kk + hi2  (kk via addr XOR kk<<5)
  const int rS = 32 * wr + l31;
  const int eB = rS * 128 + ((hi2 ^ (rS & 7)) << 4);
  // V read: row d = 32h2 + l31, granule 4wr + 2kp + hi2 (kp via addr XOR kp<<5)
  const int vB0 = l31 * 128 + (((4 * wr + hi2) ^ (l31 & 7)) << 4);
  const int vB1 = (32 + l31) * 128 + (((4 * wr + hi2) ^ (l31 & 7)) << 4);

  f32x16 oacc0 = 0.f, oacc1 = 0.f;   // partial O[t-half wc][d-half 0/1], this wave's s-half only
  float lsum = 0.f;

  // ---- prologue: stage tile 0 into buffer 0 ----
  {
    const char* g = etile + tid * 16;
#pragma unroll
    for (int c2 = 0; c2 < 4; ++c2) gll16(g + c2 * 4096, &Eb[0][0] + tid * 16 + c2 * 4096);
    const char* gv = vtile + tid * 16;
#pragma unroll
    for (int c2 = 0; c2 < 2; ++c2) gll16(gv + c2 * 4096, &Vb[0][0] + tid * 16 + c2 * 4096);
  }
  __syncthreads();

  int cur = 0;
  for (int j = 0; ; ++j) {
    // 1) issue next-tile staging (full tile of compute covers the latency)
    if (j < tb) {
      const char* g = etile + (size_t)(j + 1) * 16384 + tid * 16;
      char* l = &Eb[cur ^ 1][0] + tid * 16;
#pragma unroll
      for (int c2 = 0; c2 < 4; ++c2) gll16(g + c2 * 4096, l + c2 * 4096);
      const char* gv = vtile + (size_t)(j + 1) * 8192 + tid * 16;
      char* lv = &Vb[cur ^ 1][0] + tid * 16;
#pragma unroll
      for (int c2 = 0; c2 < 2; ++c2) gll16(gv + c2 * 4096, lv + c2 * 4096);
    }
    // 2) S^T = E·Q^T (split f16: hh + lh + hl); wave quadrant: s-half wr x t-half wc
    const char* ec = &Eb[cur][0];
    f32x16 sacc = 0.f;
#pragma unroll
    for (int kk = 0; kk < 4; ++kk) {
      f16x8 eh = *(const f16x8*)(ec + (eB ^ (kk << 5)));
      f16x8 el = *(const f16x8*)(ec + 8192 + (eB ^ (kk << 5)));
      sacc = __builtin_amdgcn_mfma_f32_32x32x16_f16(eh, qh[kk], sacc, 0, 0, 0);
      sacc = __builtin_amdgcn_mfma_f32_32x32x16_f16(el, qh[kk], sacc, 0, 0, 0);
      sacc = __builtin_amdgcn_mfma_f32_32x32x16_f16(eh, ql[kk], sacc, 0, 0, 0);
    }
    // 3) LIF + fixed-shift exp (all in registers); reg r=4rq+rr <-> s_rel = 8rq+4hi2+rr, t = tg
    float p[16];
#pragma unroll
    for (int r = 0; r < 16; ++r) {
      const float I = fmaf(gt, sacc[r], bt);
      const float L2 = __log2f((I - 1.0f) * __builtin_amdgcn_rcpf(I));  // log2((I-1)/I), firing-safe
      const float den = fmaf(-0.013862944f, L2, 0.002f);                // tau_ref - tau_rc*ln((I-1)/I)
      const float rd = __builtin_amdgcn_rcpf(den);
      // exp(score - 62.5) = 2^(score*log2e - 62.5*log2e); score = 0.125*rd
      const float pv = __builtin_amdgcn_exp2f(fmaf(0.18033688f, rd, -90.169312f));
      p[r] = (I > 1.0f + 1e-7f) ? pv : 7.1892351e-28f;                  // non-firing: exp(0 - 62.5)
    }
    if (j == tb) {                      // causal mask: only the diagonal tile needs it
#pragma unroll
      for (int rq = 0; rq < 4; ++rq)
#pragma unroll
        for (int rr = 0; rr < 4; ++rr)
          if (32 * wr + 8 * rq + 4 * hi2 + rr > 32 * wc + l31) p[4 * rq + rr] = 0.f;
    }
#pragma unroll
    for (int r = 0; r < 16; ++r) lsum += p[r];
    // 4) P -> bf16 A-frags in-register (cvt_pk + permlane32_swap), then PV partials
    const char* vc = &Vb[cur][0];
#pragma unroll
    for (int kp = 0; kp < 2; ++kp) {
      u32 x0 = cvtpk(p[8 * kp + 0], p[8 * kp + 1]);
      u32 x1 = cvtpk(p[8 * kp + 2], p[8 * kp + 3]);
      u32 y0 = cvtpk(p[8 * kp + 4], p[8 * kp + 5]);
      u32 y1 = cvtpk(p[8 * kp + 6], p[8 * kp + 7]);
      asm("v_permlane32_swap_b32 %0, %1" : "+v"(x0), "+v"(y0));
      asm("v_permlane32_swap_b32 %0, %1" : "+v"(x1), "+v"(y1));
      u32x4 af = {x0, x1, y0, y1};      // lane now holds P[t=l31][s_rel = 16kp + 8hi2 + 0..7]
      bf16x8 pa = *(bf16x8*)&af;
      bf16x8 vb0 = *(const bf16x8*)(vc + (vB0 ^ (kp << 5)));
      bf16x8 vb1 = *(const bf16x8*)(vc + (vB1 ^ (kp << 5)));
      oacc0 = __builtin_amdgcn_mfma_f32_32x32x16_bf16(pa, vb0, oacc0, 0, 0, 0);
      oacc1 = __builtin_amdgcn_mfma_f32_32x32x16_bf16(pa, vb1, oacc1, 0, 0, 0);
    }
    if (j == tb) break;
    __syncthreads();                    // staging WAR fence (drains vm+lgkm, issued a full tile ago)
    cur ^= 1;
  }

  // ---- epilogue: cross-wave (wr) reduction of O partials + lsum, once per block ----
  lsum += __shfl_xor(lsum, 32);                       // combine hi2 quarters
  if (lane < 32) LsS[wr * 64 + wc * 32 + l31] = lsum; // per-(wr, t) partial over s-half
  __syncthreads();                                    // also: all Eb reads done -> safe to reuse
  float* red = (float*)&Eb[0][0];                     // [wc][t_in_half 0..31][d 0..63] f32
  if (wr == 1) {
#pragma unroll
    for (int rq = 0; rq < 4; ++rq)
#pragma unroll
      for (int rr = 0; rr < 4; ++rr) {
        const int tr = 8 * rq + 4 * hi2 + rr;
        red[wc * 2048 + tr * 64 + l31]      = oacc0[4 * rq + rr];
        red[wc * 2048 + tr * 64 + 32 + l31] = oacc1[4 * rq + rr];
      }
  }
  __syncthreads();
  if (wr == 0) {
    float* ob = out + ((size_t)(b * Hh + h) * Tt + t0 + 32 * wc) * 64;
#pragma unroll
    for (int rq = 0; rq < 4; ++rq) {
      const int tr0 = 8 * rq + 4 * hi2;
      f32x4 lt0 = *(const f32x4*)&LsS[wc * 32 + tr0];        // broadcast reads
      f32x4 lt1 = *(const f32x4*)&LsS[64 + wc * 32 + tr0];
#pragma unroll
      for (int rr = 0; rr < 4; ++rr) {
        const int tr = tr0 + rr;
        const float linv = __builtin_amdgcn_rcpf(lt0[rr] + lt1[rr]);
        const float o0 = oacc0[4 * rq + rr] + red[wc * 2048 + tr * 64 + l31];
        const float o1 = oacc1[4 * rq + rr] + red[wc * 2048 + tr * 64 + 32 + l31];
        ob[(size_t)tr * 64 + l31]      = o0 * linv;
        ob[(size_t)tr * 64 + 32 + l31] = o1 * linv;
      }
    }
  }
}

extern "C" void kernel_launch(void* const* d_in, const int* in_sizes, int n_in,
                              void* d_out, int out_size, void* d_ws, size_t ws_size,
                              hipStream_t stream) {
  const float* Q    = (const float*)d_in[0];
  // d_in[1] = K is UNUSED by the reference (scores use enc_hat)
  const float* V    = (const float*)d_in[2];
  const float* E    = (const float*)d_in[3];
  const float* gain = (const float*)d_in[4];
  const float* bias = (const float*)d_in[5];
  float* out = (float*)d_out;

  constexpr size_t EIMG_BYTES = (size_t)Hh * 32 * 16384;        // 8 MiB
  char* Eimg = (char*)d_ws;
  char* Vimg = (char*)d_ws + EIMG_BYTES;                        // 8 MiB

  prep_e<<<Hh * 32, 256, 0, stream>>>(E, Eimg);
  prep_v<<<Bb * Hh * 32, 256, 0, stream>>>(V, Vimg);
  lif_attn6<<<1024, 256, 0, stream>>>(Q, gain, bias, Eimg, Vimg, out);
}

// Round 8
// 73.998 us; speedup vs baseline: 3.1905x; 1.0724x over previous
//
#include <hip/hip_runtime.h>
#include <hip/hip_bf16.h>
#include <math.h>

constexpr int Bb = 2, Hh = 16, Tt = 2048;

typedef __attribute__((ext_vector_type(8))) _Float16 f16x8;
typedef __attribute__((ext_vector_type(8))) short bf16x8;
typedef __attribute__((ext_vector_type(4))) float f32x4;
typedef __attribute__((ext_vector_type(16))) float f32x16;
typedef __attribute__((ext_vector_type(4))) unsigned int u32x4;
typedef unsigned int u32;

__device__ __forceinline__ short f2bf(float x){ __hip_bfloat16 h = __float2bfloat16(x); return *(short*)&h; }
// 64-elem-row swizzle helpers (prep_v's internal transpose)
__device__ __forceinline__ int swze(int row, int e){ return row*64 + ((((e>>3) ^ (row&7))<<3) | (e&7)); }
__device__ __forceinline__ int swzg(int row, int e0){ return row*64 + ((((e0>>3) ^ (row&7))<<3)); }

__device__ __forceinline__ void gll16(const void* g, void* l){
  __builtin_amdgcn_global_load_lds((const __attribute__((address_space(1))) u32*)g,
                                   (__attribute__((address_space(3))) u32*)l, 16, 0, 0);
}
__device__ __forceinline__ u32 cvtpk(float lo, float hi){
  u32 d; asm("v_cvt_pk_bf16_f32 %0, %1, %2" : "=v"(d) : "v"(lo), "v"(hi)); return d;
}

// ---------- prep 1: E fp32 -> f16 hi/lo 64x64 tile images, XOR-swizzled (LDS byte-exact) ----------
__global__ __launch_bounds__(256) void prep_e(const float* __restrict__ E, char* __restrict__ Eimg){
  const float* src = E + (size_t)blockIdx.x * 4096;
  char* dst = Eimg + (size_t)blockIdx.x * 16384;
#pragma unroll
  for (int i = 0; i < 2; ++i) {
    const int gid = threadIdx.x + 256 * i;
    const int row = gid >> 3, gc = gid & 7;
    const float* s8 = src + row * 64 + gc * 8;
    float4 a = *(const float4*)s8;
    float4 c = *(const float4*)(s8 + 4);
    float v[8] = {a.x, a.y, a.z, a.w, c.x, c.y, c.z, c.w};
    f16x8 hv, lv;
#pragma unroll
    for (int k = 0; k < 8; ++k) {
      _Float16 hi = (_Float16)v[k];
      hv[k] = hi; lv[k] = (_Float16)(v[k] - (float)hi);
    }
    const int off = row * 128 + ((gc ^ (row & 7)) << 4);
    *(f16x8*)(dst + off) = hv;
    *(f16x8*)(dst + 8192 + off) = lv;
  }
}

// ---------- prep 2: V fp32 [bh][s][d] -> bf16 transposed GRANULE-MAJOR tiles: [g8][d] 16B granules ----------
// tile offset (g8, d) = g8*1024 + d*16 holds Vt[d][s = 8*g8 .. 8*g8+7] (bf16)
__global__ __launch_bounds__(256) void prep_v(const float* __restrict__ V, char* __restrict__ Vimg){
  __shared__ __align__(16) short Tl[64 * 64];
  const int tid = threadIdx.x;
  const int j = blockIdx.x & 31, bh = blockIdx.x >> 5;
  const int s0 = j * 64;
  {
    const int r = tid >> 2, c0 = (tid & 3) * 16;
    const float* src = V + ((size_t)bh * Tt + s0 + r) * 64 + c0;
#pragma unroll
    for (int i = 0; i < 4; ++i) {
      float4 t4 = ((const float4*)src)[i];
      float vv[4] = {t4.x, t4.y, t4.z, t4.w};
#pragma unroll
      for (int k = 0; k < 4; ++k) Tl[swze(c0 + 4 * i + k, r)] = f2bf(vv[k]);
    }
  }
  __syncthreads();
  {
    const int d = tid >> 2, sg = (tid & 3) * 16;
    bf16x8 a = *(const bf16x8*)&Tl[swzg(d, sg)];
    bf16x8 b = *(const bf16x8*)&Tl[swzg(d, sg + 8)];
    char* dst = Vimg + (size_t)blockIdx.x * 8192;
    *(bf16x8*)(dst + (sg >> 3) * 1024 + d * 16)       = a;
    *(bf16x8*)(dst + ((sg >> 3) + 1) * 1024 + d * 16) = b;
  }
}

// ---------- main: pipelined flash LIF-attention: S(j+1) MFMA || LIF(j) VALU, V in registers ----------
__global__ __launch_bounds__(256, 3) void lif_attn8(
    const float* __restrict__ Q, const float* __restrict__ gain, const float* __restrict__ bias,
    const char* __restrict__ Eimg, const char* __restrict__ Vimg, float* __restrict__ out)
{
  __shared__ __align__(16) char Eb[2][16384];   // E tile hi+lo, double-buffered (reused as red[] in epilogue)
  __shared__ __align__(16) float LsS[128];      // lsum partials [wr][wc][t_in_half]

  const int tid = threadIdx.x, lane = tid & 63;
  const int l31 = lane & 31, hi2 = lane >> 5;
  const int w = tid >> 6, wc = w & 1, wr = w >> 1;  // wc = t-half; wr = s-half
  const int bh = blockIdx.x & 31, tb = 31 - (blockIdx.x >> 5);  // big tiles dispatched first
  const int b = bh >> 4, h = bh & 15, t0 = tb * 64;
  const int tg = t0 + 32 * wc + l31;            // this lane's query row

  const char* etile = Eimg + (size_t)(h * 32) * 16384;
  const char* vtile = Vimg + (size_t)(bh * 32) * 8192;

  // ---- Q fragments f16 hi/lo (loop-invariant, B-operand: k = 16kk + 8hi2 + j) ----
  f16x8 qh[4], ql[4];
  {
    const float* qp = Q + ((size_t)(b * Hh + h) * Tt + tg) * 64 + 8 * hi2;
#pragma unroll
    for (int kk = 0; kk < 4; ++kk) {
      const float* p0 = qp + 16 * kk;
      float4 a = *(const float4*)p0;
      float4 c = *(const float4*)(p0 + 4);
      float v[8] = {a.x, a.y, a.z, a.w, c.x, c.y, c.z, c.w};
#pragma unroll
      for (int k = 0; k < 8; ++k) {
        _Float16 hi = (_Float16)v[k];
        qh[kk][k] = hi; ql[kk][k] = (_Float16)(v[k] - (float)hi);
      }
    }
  }
  const float gt = gain[h * Tt + tg], bt = bias[h * Tt + tg];

  // E LDS read base: row rS = 32wr + l31, granule 2kk + hi2 (kk via addr XOR kk<<5)
  const int rS = 32 * wr + l31;
  const int eB = rS * 128 + ((hi2 ^ (rS & 7)) << 4);

  // V global-load lane pointers (granule-major tiles; coalesced 16B/lane)
  const int g8a = 4 * wr + hi2;
  const char* vp0 = vtile + g8a * 1024 + l31 * 16;
  const char* vp1 = vtile + g8a * 1024 + (32 + l31) * 16;
  const char* vp2 = vtile + (g8a + 2) * 1024 + l31 * 16;
  const char* vp3 = vtile + (g8a + 2) * 1024 + (32 + l31) * 16;

  f32x16 oacc0 = 0.f, oacc1 = 0.f;   // partial O[t-half wc][d 0..31 / 32..63], this wave's s-half
  float lsum = 0.f;
  f32x16 sA, sB;
  bf16x8 vA[4], vB[4];

  auto STAGE_E = [&](int n, int buf) {
    const char* g = etile + (size_t)n * 16384 + tid * 16;
    char* l = &Eb[buf][0] + tid * 16;
#pragma unroll
    for (int c2 = 0; c2 < 4; ++c2) gll16(g + c2 * 4096, l + c2 * 4096);
  };
  auto SSTEP = [&](int buf, f32x16& acc) {   // S^T = E·Q^T, split f16 (hh + lh + hl)
    const char* ec = &Eb[buf][0];
    acc = 0.f;
#pragma unroll
    for (int kk = 0; kk < 4; ++kk) {
      f16x8 eh = *(const f16x8*)(ec + (eB ^ (kk << 5)));
      f16x8 el = *(const f16x8*)(ec + 8192 + (eB ^ (kk << 5)));
      acc = __builtin_amdgcn_mfma_f32_32x32x16_f16(eh, qh[kk], acc, 0, 0, 0);
      acc = __builtin_amdgcn_mfma_f32_32x32x16_f16(el, qh[kk], acc, 0, 0, 0);
      acc = __builtin_amdgcn_mfma_f32_32x32x16_f16(eh, ql[kk], acc, 0, 0, 0);
    }
  };
  auto VLOAD = [&](int n, bf16x8* vv) {
    const size_t o = (size_t)n * 8192;
    vv[0] = *(const bf16x8*)(vp0 + o);
    vv[1] = *(const bf16x8*)(vp1 + o);
    vv[2] = *(const bf16x8*)(vp2 + o);
    vv[3] = *(const bf16x8*)(vp3 + o);
  };

  // BODY(j): issue stage E(j+2); S(j+1) -> nxt (MFMA stream) || LIF(j) on cur (VALU stream); PV(j); barrier
  auto BODY = [&](int j, f32x16& cur, f32x16& nxt, bf16x8* vc, bf16x8* vn) {
    if (j + 2 <= tb) STAGE_E(j + 2, j & 1);
    if (j + 1 <= tb) { SSTEP((j + 1) & 1, nxt); VLOAD(j + 1, vn); }
    // LIF + fixed-shift exp; reg r=4rq+rr <-> s_rel = 32wr + 8rq + 4hi2 + rr, t = tg
    float p[16];
#pragma unroll
    for (int r = 0; r < 16; ++r) {
      const float I = fmaf(gt, cur[r], bt);
      const float L2 = __log2f((I - 1.0f) * __builtin_amdgcn_rcpf(I));  // log2((I-1)/I), firing-safe
      const float den = fmaf(-0.013862944f, L2, 0.002f);                // tau_ref - tau_rc*ln((I-1)/I)
      const float rd = __builtin_amdgcn_rcpf(den);
      const float pv = __builtin_amdgcn_exp2f(fmaf(0.18033688f, rd, -90.169312f));  // exp(score-62.5)
      p[r] = (I > 1.0f + 1e-7f) ? pv : 7.1892351e-28f;                  // non-firing: exp(0 - 62.5)
    }
    if (j == tb) {                      // causal mask: only the diagonal tile
#pragma unroll
      for (int rq = 0; rq < 4; ++rq)
#pragma unroll
        for (int rr = 0; rr < 4; ++rr)
          if (32 * wr + 8 * rq + 4 * hi2 + rr > 32 * wc + l31) p[4 * rq + rr] = 0.f;
    }
#pragma unroll
    for (int r = 0; r < 16; ++r) lsum += p[r];
    // PV: pack P to bf16 A-frags in-register (cvt_pk + permlane32_swap), V from registers
#pragma unroll
    for (int kp = 0; kp < 2; ++kp) {
      u32 x0 = cvtpk(p[8 * kp + 0], p[8 * kp + 1]);
      u32 x1 = cvtpk(p[8 * kp + 2], p[8 * kp + 3]);
      u32 y0 = cvtpk(p[8 * kp + 4], p[8 * kp + 5]);
      u32 y1 = cvtpk(p[8 * kp + 6], p[8 * kp + 7]);
      asm("v_permlane32_swap_b32 %0, %1" : "+v"(x0), "+v"(y0));
      asm("v_permlane32_swap_b32 %0, %1" : "+v"(x1), "+v"(y1));
      u32x4 af = {x0, x1, y0, y1};      // lane holds P[t=l31][s_rel = 32wr + 16kp + 8hi2 + 0..7]
      bf16x8 pa = *(bf16x8*)&af;
      oacc0 = __builtin_amdgcn_mfma_f32_32x32x16_bf16(pa, vc[2 * kp + 0], oacc0, 0, 0, 0);
      oacc1 = __builtin_amdgcn_mfma_f32_32x32x16_bf16(pa, vc[2 * kp + 1], oacc1, 0, 0, 0);
    }
    __syncthreads();   // completes this body's stage/loads; WAR-protects Eb buffers
  };

  // ---- prologue: E(0),E(1),V(0); S(0) ----
  STAGE_E(0, 0);
  if (tb >= 1) STAGE_E(1, 1);
  VLOAD(0, vA);
  __syncthreads();
  SSTEP(0, sA);
  __syncthreads();    // all waves done reading Eb[0] before BODY(0) stages E(2) into it

  int j = 0;
  for (;;) {
    BODY(j, sA, sB, vA, vB); if (j == tb) break; ++j;
    BODY(j, sB, sA, vB, vA); if (j == tb) break; ++j;
  }

  // ---- epilogue: cross-wave (wr) reduction of O partials + lsum, once per block ----
  lsum += __shfl_xor(lsum, 32);                       // combine hi2 quarters
  if (lane < 32) LsS[wr * 64 + wc * 32 + l31] = lsum; // per-(wr, t) partial over s-half
  __syncthreads();
  float* red = (float*)&Eb[0][0];                     // [wc][t_in_half 0..31][d 0..63] f32
  if (wr == 1) {
#pragma unroll
    for (int rq = 0; rq < 4; ++rq)
#pragma unroll
      for (int rr = 0; rr < 4; ++rr) {
        const int tr = 8 * rq + 4 * hi2 + rr;
        red[wc * 2048 + tr * 64 + l31]      = oacc0[4 * rq + rr];
        red[wc * 2048 + tr * 64 + 32 + l31] = oacc1[4 * rq + rr];
      }
  }
  __syncthreads();
  if (wr == 0) {
    float* ob = out + ((size_t)(b * Hh + h) * Tt + t0 + 32 * wc) * 64;
#pragma unroll
    for (int rq = 0; rq < 4; ++rq) {
      const int tr0 = 8 * rq + 4 * hi2;
      f32x4 lt0 = *(const f32x4*)&LsS[wc * 32 + tr0];        // broadcast reads
      f32x4 lt1 = *(const f32x4*)&LsS[64 + wc * 32 + tr0];
#pragma unroll
      for (int rr = 0; rr < 4; ++rr) {
        const int tr = tr0 + rr;
        const float linv = __builtin_amdgcn_rcpf(lt0[rr] + lt1[rr]);
        const float o0 = oacc0[4 * rq + rr] + red[wc * 2048 + tr * 64 + l31];
        const float o1 = oacc1[4 * rq + rr] + red[wc * 2048 + tr * 64 + 32 + l31];
        ob[(size_t)tr * 64 + l31]      = o0 * linv;
        ob[(size_t)tr * 64 + 32 + l31] = o1 * linv;
      }
    }
  }
}

extern "C" void kernel_launch(void* const* d_in, const int* in_sizes, int n_in,
                              void* d_out, int out_size, void* d_ws, size_t ws_size,
                              hipStream_t stream) {
  const float* Q    = (const float*)d_in[0];
  // d_in[1] = K is UNUSED by the reference (scores use enc_hat)
  const float* V    = (const float*)d_in[2];
  const float* E    = (const float*)d_in[3];
  const float* gain = (const float*)d_in[4];
  const float* bias = (const float*)d_in[5];
  float* out = (float*)d_out;

  constexpr size_t EIMG_BYTES = (size_t)Hh * 32 * 16384;        // 8 MiB
  char* Eimg = (char*)d_ws;
  char* Vimg = (char*)d_ws + EIMG_BYTES;                        // 8 MiB

  prep_e<<<Hh * 32, 256, 0, stream>>>(E, Eimg);
  prep_v<<<Bb * Hh * 32, 256, 0, stream>>>(V, Vimg);
  lif_attn8<<<1024, 256, 0, stream>>>(Q, gain, bias, Eimg, Vimg, out);
}

// Round 9
// 73.688 us; speedup vs baseline: 3.2039x; 1.0042x over previous
//
#include <hip/hip_runtime.h>
#include <hip/hip_bf16.h>
#include <math.h>

constexpr int Bb = 2, Hh = 16, Tt = 2048;

typedef __attribute__((ext_vector_type(8))) _Float16 f16x8;
typedef __attribute__((ext_vector_type(8))) short bf16x8;
typedef __attribute__((ext_vector_type(4))) float f32x4;
typedef __attribute__((ext_vector_type(16))) float f32x16;
typedef __attribute__((ext_vector_type(4))) unsigned int u32x4;
typedef unsigned int u32;

__device__ __forceinline__ short f2bf(float x){ __hip_bfloat16 h = __float2bfloat16(x); return *(short*)&h; }
// 64-elem-row swizzle helpers (prep_v's internal transpose)
__device__ __forceinline__ int swze(int row, int e){ return row*64 + ((((e>>3) ^ (row&7))<<3) | (e&7)); }
__device__ __forceinline__ int swzg(int row, int e0){ return row*64 + ((((e0>>3) ^ (row&7))<<3)); }

__device__ __forceinline__ void gll16(const void* g, void* l){
  __builtin_amdgcn_global_load_lds((const __attribute__((address_space(1))) u32*)g,
                                   (__attribute__((address_space(3))) u32*)l, 16, 0, 0);
}
__device__ __forceinline__ u32 cvtpk(float lo, float hi){
  u32 d; asm("v_cvt_pk_bf16_f32 %0, %1, %2" : "=v"(d) : "v"(lo), "v"(hi)); return d;
}

// ---------- prep 1: E fp32 -> f16 hi/lo 64x64 tile images, XOR-swizzled (LDS byte-exact) ----------
__global__ __launch_bounds__(256) void prep_e(const float* __restrict__ E, char* __restrict__ Eimg){
  const float* src = E + (size_t)blockIdx.x * 4096;
  char* dst = Eimg + (size_t)blockIdx.x * 16384;
#pragma unroll
  for (int i = 0; i < 2; ++i) {
    const int gid = threadIdx.x + 256 * i;
    const int row = gid >> 3, gc = gid & 7;
    const float* s8 = src + row * 64 + gc * 8;
    float4 a = *(const float4*)s8;
    float4 c = *(const float4*)(s8 + 4);
    float v[8] = {a.x, a.y, a.z, a.w, c.x, c.y, c.z, c.w};
    f16x8 hv, lv;
#pragma unroll
    for (int k = 0; k < 8; ++k) {
      _Float16 hi = (_Float16)v[k];
      hv[k] = hi; lv[k] = (_Float16)(v[k] - (float)hi);
    }
    const int off = row * 128 + ((gc ^ (row & 7)) << 4);
    *(f16x8*)(dst + off) = hv;
    *(f16x8*)(dst + 8192 + off) = lv;
  }
}

// ---------- prep 2: V fp32 [bh][s][d] -> bf16 transposed GRANULE-MAJOR tiles: [g8][d] 16B granules ----------
__global__ __launch_bounds__(256) void prep_v(const float* __restrict__ V, char* __restrict__ Vimg){
  __shared__ __align__(16) short Tl[64 * 64];
  const int tid = threadIdx.x;
  const int j = blockIdx.x & 31, bh = blockIdx.x >> 5;
  const int s0 = j * 64;
  {
    const int r = tid >> 2, c0 = (tid & 3) * 16;
    const float* src = V + ((size_t)bh * Tt + s0 + r) * 64 + c0;
#pragma unroll
    for (int i = 0; i < 4; ++i) {
      float4 t4 = ((const float4*)src)[i];
      float vv[4] = {t4.x, t4.y, t4.z, t4.w};
#pragma unroll
      for (int k = 0; k < 4; ++k) Tl[swze(c0 + 4 * i + k, r)] = f2bf(vv[k]);
    }
  }
  __syncthreads();
  {
    const int d = tid >> 2, sg = (tid & 3) * 16;
    bf16x8 a = *(const bf16x8*)&Tl[swzg(d, sg)];
    bf16x8 b = *(const bf16x8*)&Tl[swzg(d, sg + 8)];
    char* dst = Vimg + (size_t)blockIdx.x * 8192;
    *(bf16x8*)(dst + (sg >> 3) * 1024 + d * 16)       = a;
    *(bf16x8*)(dst + ((sg >> 3) + 1) * 1024 + d * 16) = b;
  }
}

// ---------- main: pipelined flash LIF-attention, counted-vmcnt raw barriers ----------
__global__ __launch_bounds__(256, 3) void lif_attn9(
    const float* __restrict__ Q, const float* __restrict__ gain, const float* __restrict__ bias,
    const char* __restrict__ Eimg, const char* __restrict__ Vimg, float* __restrict__ out)
{
  __shared__ __align__(16) char Eb[2][16384];   // E tile hi+lo, double-buffered (reused as red[] in epilogue)
  __shared__ __align__(16) float LsS[128];      // lsum partials [wr][wc][t_in_half]

  const int tid = threadIdx.x, lane = tid & 63;
  const int l31 = lane & 31, hi2 = lane >> 5;
  const int w = tid >> 6, wc = w & 1, wr = w >> 1;  // wc = t-half; wr = s-half
  const int bh = blockIdx.x & 31, tb = 31 - (blockIdx.x >> 5);  // big tiles dispatched first
  const int b = bh >> 4, h = bh & 15, t0 = tb * 64;
  const int tg = t0 + 32 * wc + l31;            // this lane's query row

  const char* etile = Eimg + (size_t)(h * 32) * 16384;
  const char* vtile = Vimg + (size_t)(bh * 32) * 8192;

  // ---- Q fragments f16 hi/lo (loop-invariant, B-operand: k = 16kk + 8hi2 + j) ----
  f16x8 qh[4], ql[4];
  {
    const float* qp = Q + ((size_t)(b * Hh + h) * Tt + tg) * 64 + 8 * hi2;
#pragma unroll
    for (int kk = 0; kk < 4; ++kk) {
      const float* p0 = qp + 16 * kk;
      float4 a = *(const float4*)p0;
      float4 c = *(const float4*)(p0 + 4);
      float v[8] = {a.x, a.y, a.z, a.w, c.x, c.y, c.z, c.w};
#pragma unroll
      for (int k = 0; k < 8; ++k) {
        _Float16 hi = (_Float16)v[k];
        qh[kk][k] = hi; ql[kk][k] = (_Float16)(v[k] - (float)hi);
      }
    }
  }
  const float gt = gain[h * Tt + tg], bt = bias[h * Tt + tg];

  // E LDS read base: row rS = 32wr + l31, granule 2kk + hi2 (kk via addr XOR kk<<5)
  const int rS = 32 * wr + l31;
  const int eB = rS * 128 + ((hi2 ^ (rS & 7)) << 4);

  // V global-load lane pointers (granule-major tiles; coalesced 16B/lane)
  const int g8a = 4 * wr + hi2;
  const char* vp0 = vtile + g8a * 1024 + l31 * 16;
  const char* vp1 = vtile + g8a * 1024 + (32 + l31) * 16;
  const char* vp2 = vtile + (g8a + 2) * 1024 + l31 * 16;
  const char* vp3 = vtile + (g8a + 2) * 1024 + (32 + l31) * 16;

  f32x16 oacc0 = 0.f, oacc1 = 0.f;   // partial O[t-half wc][d 0..31 / 32..63], this wave's s-half
  float lsum = 0.f;
  f32x16 sA, sB;
  bf16x8 vA[4], vB[4];

  auto STAGE_E = [&](int n, int buf) {
    const char* g = etile + (size_t)n * 16384 + tid * 16;
    char* l = &Eb[buf][0] + tid * 16;
#pragma unroll
    for (int c2 = 0; c2 < 4; ++c2) gll16(g + c2 * 4096, l + c2 * 4096);
  };
  auto SSTEP = [&](int buf, f32x16& acc) {   // S^T = E·Q^T, split f16 (hh + lh + hl)
    const char* ec = &Eb[buf][0];
    acc = 0.f;
    __builtin_amdgcn_s_setprio(1);
#pragma unroll
    for (int kk = 0; kk < 4; ++kk) {
      f16x8 eh = *(const f16x8*)(ec + (eB ^ (kk << 5)));
      f16x8 el = *(const f16x8*)(ec + 8192 + (eB ^ (kk << 5)));
      acc = __builtin_amdgcn_mfma_f32_32x32x16_f16(eh, qh[kk], acc, 0, 0, 0);
      acc = __builtin_amdgcn_mfma_f32_32x32x16_f16(el, qh[kk], acc, 0, 0, 0);
      acc = __builtin_amdgcn_mfma_f32_32x32x16_f16(eh, ql[kk], acc, 0, 0, 0);
    }
    __builtin_amdgcn_s_setprio(0);
  };
  auto VLOAD = [&](int n, bf16x8* vv) {
    const size_t o = (size_t)n * 8192;
    vv[0] = *(const bf16x8*)(vp0 + o);
    vv[1] = *(const bf16x8*)(vp1 + o);
    vv[2] = *(const bf16x8*)(vp2 + o);
    vv[3] = *(const bf16x8*)(vp3 + o);
  };

  // BODY(j): stage E(j+2) [vm order pinned first]; S(j+1) MFMA || LIF(j) VALU; PV(j);
  //          end: s_waitcnt vmcnt(4) [E(j+2) resident, V(j+1) still in flight] + raw barrier.
  auto BODY = [&](int j, f32x16& cur, f32x16& nxt, bf16x8* vc, bf16x8* vn) {
    if (j + 2 <= tb) STAGE_E(j + 2, j & 1);
    __builtin_amdgcn_sched_barrier(0);        // pin vm issue order: E-stage before V-loads
    if (j + 1 <= tb) { SSTEP((j + 1) & 1, nxt); VLOAD(j + 1, vn); }
    // LIF + fixed-shift exp; branchless: a<0 for non-firing I -> NaN chain -> fmaxf picks e^-62.5
    float p[16];
#pragma unroll
    for (int r = 0; r < 16; ++r) {
      const float I = fmaf(gt, cur[r], bt);
      const float a = (I - 1.0f) * __builtin_fabsf(__builtin_amdgcn_rcpf(I));
      const float L2 = __log2f(a);                                      // NaN unless I > 1
      const float den = fmaf(-0.013862944f, L2, 0.002f);                // tau_ref - tau_rc*ln((I-1)/I)
      const float rd = __builtin_amdgcn_rcpf(den);
      const float pv = __builtin_amdgcn_exp2f(fmaf(0.18033688f, rd, -90.169312f));  // exp(score-62.5)
      p[r] = fmaxf(pv, 7.1892351e-28f);                                 // non-firing: exp(0 - 62.5)
    }
    if (j == tb) {                      // causal mask: only the diagonal tile
#pragma unroll
      for (int rq = 0; rq < 4; ++rq)
#pragma unroll
        for (int rr = 0; rr < 4; ++rr)
          if (32 * wr + 8 * rq + 4 * hi2 + rr > 32 * wc + l31) p[4 * rq + rr] = 0.f;
    }
#pragma unroll
    for (int r = 0; r < 16; ++r) lsum += p[r];
    // PV: pack P to bf16 A-frags in-register (cvt_pk + permlane32_swap), V from registers
    __builtin_amdgcn_s_setprio(1);
#pragma unroll
    for (int kp = 0; kp < 2; ++kp) {
      u32 x0 = cvtpk(p[8 * kp + 0], p[8 * kp + 1]);
      u32 x1 = cvtpk(p[8 * kp + 2], p[8 * kp + 3]);
      u32 y0 = cvtpk(p[8 * kp + 4], p[8 * kp + 5]);
      u32 y1 = cvtpk(p[8 * kp + 6], p[8 * kp + 7]);
      asm("v_permlane32_swap_b32 %0, %1" : "+v"(x0), "+v"(y0));
      asm("v_permlane32_swap_b32 %0, %1" : "+v"(x1), "+v"(y1));
      u32x4 af = {x0, x1, y0, y1};      // lane holds P[t=l31][s_rel = 32wr + 16kp + 8hi2 + 0..7]
      bf16x8 pa = *(bf16x8*)&af;
      oacc0 = __builtin_amdgcn_mfma_f32_32x32x16_bf16(pa, vc[2 * kp + 0], oacc0, 0, 0, 0);
      oacc1 = __builtin_amdgcn_mfma_f32_32x32x16_bf16(pa, vc[2 * kp + 1], oacc1, 0, 0, 0);
    }
    __builtin_amdgcn_s_setprio(0);
  };

  // ---- prologue: E(0),E(1),V(0); S(0) ----
  STAGE_E(0, 0);
  if (tb >= 1) STAGE_E(1, 1);
  __builtin_amdgcn_sched_barrier(0);
  VLOAD(0, vA);
  asm volatile("s_waitcnt vmcnt(4)" ::: "memory");   // E(0),E(1) resident; V(0) in flight
  __builtin_amdgcn_s_barrier();
  __builtin_amdgcn_sched_barrier(0);
  SSTEP(0, sA);
  asm volatile("s_waitcnt vmcnt(4)" ::: "memory");
  __builtin_amdgcn_s_barrier();                      // WAR: Eb[0] reads done before BODY(0) restages it
  __builtin_amdgcn_sched_barrier(0);

  int j = 0;
  for (;;) {
    BODY(j, sA, sB, vA, vB);
    if (j == tb) break;
    asm volatile("s_waitcnt vmcnt(4)" ::: "memory"); // E(j+2) resident; V(j+1) stays in flight
    __builtin_amdgcn_s_barrier();
    __builtin_amdgcn_sched_barrier(0);
    ++j;
    BODY(j, sB, sA, vB, vA);
    if (j == tb) break;
    asm volatile("s_waitcnt vmcnt(4)" ::: "memory");
    __builtin_amdgcn_s_barrier();
    __builtin_amdgcn_sched_barrier(0);
    ++j;
  }

  // ---- epilogue: cross-wave (wr) reduction of O partials + lsum, once per block ----
  lsum += __shfl_xor(lsum, 32);                       // combine hi2 quarters
  if (lane < 32) LsS[wr * 64 + wc * 32 + l31] = lsum; // per-(wr, t) partial over s-half
  __syncthreads();                                    // full drain; Eb safe to reuse below
  float* red = (float*)&Eb[0][0];                     // [wc][t_in_half 0..31][d 0..63] f32
  if (wr == 1) {
#pragma unroll
    for (int rq = 0; rq < 4; ++rq)
#pragma unroll
      for (int rr = 0; rr < 4; ++rr) {
        const int tr = 8 * rq + 4 * hi2 + rr;
        red[wc * 2048 + tr * 64 + l31]      = oacc0[4 * rq + rr];
        red[wc * 2048 + tr * 64 + 32 + l31] = oacc1[4 * rq + rr];
      }
  }
  __syncthreads();
  if (wr == 0) {
    float* ob = out + ((size_t)(b * Hh + h) * Tt + t0 + 32 * wc) * 64;
#pragma unroll
    for (int rq = 0; rq < 4; ++rq) {
      const int tr0 = 8 * rq + 4 * hi2;
      f32x4 lt0 = *(const f32x4*)&LsS[wc * 32 + tr0];        // broadcast reads
      f32x4 lt1 = *(const f32x4*)&LsS[64 + wc * 32 + tr0];
#pragma unroll
      for (int rr = 0; rr < 4; ++rr) {
        const int tr = tr0 + rr;
        const float linv = __builtin_amdgcn_rcpf(lt0[rr] + lt1[rr]);
        const float o0 = oacc0[4 * rq + rr] + red[wc * 2048 + tr * 64 + l31];
        const float o1 = oacc1[4 * rq + rr] + red[wc * 2048 + tr * 64 + 32 + l31];
        ob[(size_t)tr * 64 + l31]      = o0 * linv;
        ob[(size_t)tr * 64 + 32 + l31] = o1 * linv;
      }
    }
  }
}

extern "C" void kernel_launch(void* const* d_in, const int* in_sizes, int n_in,
                              void* d_out, int out_size, void* d_ws, size_t ws_size,
                              hipStream_t stream) {
  const float* Q    = (const float*)d_in[0];
  // d_in[1] = K is UNUSED by the reference (scores use enc_hat)
  const float* V    = (const float*)d_in[2];
  const float* E    = (const float*)d_in[3];
  const float* gain = (const float*)d_in[4];
  const float* bias = (const float*)d_in[5];
  float* out = (float*)d_out;

  constexpr size_t EIMG_BYTES = (size_t)Hh * 32 * 16384;        // 8 MiB
  char* Eimg = (char*)d_ws;
  char* Vimg = (char*)d_ws + EIMG_BYTES;                        // 8 MiB

  prep_e<<<Hh * 32, 256, 0, stream>>>(E, Eimg);
  prep_v<<<Bb * Hh * 32, 256, 0, stream>>>(V, Vimg);
  lif_attn9<<<1024, 256, 0, stream>>>(Q, gain, bias, Eimg, Vimg, out);
}